// Round 1
// baseline (51227.875 us; speedup 1.0000x reference)
//
#include <hip/hip_runtime.h>
#include <stdint.h>

#define BB 512
#define TT 256
#define HH 512
#define NCC 512
#define KIN 272   // SKEL + GEN

// ---------------- threefry2x32 (JAX-exact, 20 rounds) ----------------
__device__ __forceinline__ void tf_round(uint32_t &x0, uint32_t &x1, int r) {
  x0 += x1;
  x1 = (x1 << r) | (x1 >> (32 - r));
  x1 ^= x0;
}

__device__ __forceinline__ void threefry2x32(uint32_t k0, uint32_t k1,
                                             uint32_t c0, uint32_t c1,
                                             uint32_t &o0, uint32_t &o1) {
  uint32_t ks2 = k0 ^ k1 ^ 0x1BD11BDAu;
  uint32_t x0 = c0 + k0, x1 = c1 + k1;
  tf_round(x0, x1, 13); tf_round(x0, x1, 15); tf_round(x0, x1, 26); tf_round(x0, x1, 6);
  x0 += k1;  x1 += ks2 + 1u;
  tf_round(x0, x1, 17); tf_round(x0, x1, 29); tf_round(x0, x1, 16); tf_round(x0, x1, 24);
  x0 += ks2; x1 += k0 + 2u;
  tf_round(x0, x1, 13); tf_round(x0, x1, 15); tf_round(x0, x1, 26); tf_round(x0, x1, 6);
  x0 += k0;  x1 += k1 + 3u;
  tf_round(x0, x1, 17); tf_round(x0, x1, 29); tf_round(x0, x1, 16); tf_round(x0, x1, 24);
  x0 += k1;  x1 += ks2 + 4u;
  tf_round(x0, x1, 13); tf_round(x0, x1, 15); tf_round(x0, x1, 26); tf_round(x0, x1, 6);
  x0 += ks2; x1 += k0 + 5u;
  o0 = x0; o1 = x1;
}

// ---------------- init: h1 = concat(note, genre) @ W_hid.T + b_hid; tok = 0 ----
__global__ void __launch_bounds__(256) init_kernel(
    const float* __restrict__ note, const float* __restrict__ genre,
    const float* __restrict__ Whid, const float* __restrict__ bhid,
    double* __restrict__ h1, int* __restrict__ tok) {
  int b = blockIdx.x;
  int tid = threadIdx.x;
  __shared__ double u[KIN];
  if (tid < 256) u[tid] = (double)note[b * 256 + tid];
  if (tid < 16)  u[256 + tid] = (double)genre[b * 16 + tid];
  if (tid == 0)  tok[b] = 0;
  __syncthreads();
  for (int j = tid; j < HH; j += 256) {
    double acc = 0.0;
    const float* w = Whid + (size_t)j * KIN;
    #pragma unroll 4
    for (int k = 0; k < KIN; ++k) acc = fma(u[k], (double)w[k], acc);
    h1[(size_t)b * HH + j] = acc + (double)bhid[j];
  }
}

// ---------------- fused GRU cell step ----------------
// computes h_out = GRUCell(x, h_prev) for a 32(batch) x 32(hidden-col) tile.
// x_mode 0: x = emb[tok[b]] (f32 gather); x_mode 1: x = xf64 (f64 matrix).
#define BK 32
__global__ void __launch_bounds__(256) gru_kernel(
    const float* __restrict__ Wih, const float* __restrict__ Whh,
    const float* __restrict__ bih, const float* __restrict__ bhh,
    const double* __restrict__ hprev, double* __restrict__ hout,
    const double* __restrict__ xf64,
    const float* __restrict__ emb, const int* __restrict__ tok, int x_mode) {
  __shared__ double xs[BK][BK + 1];
  __shared__ double hs[BK][BK + 1];
  __shared__ float  ws[6][BK][BK + 1];
  __shared__ int    stok[BK];

  int tid = threadIdx.x;
  int j0 = blockIdx.x * BK;   // hidden-col tile
  int b0 = blockIdx.y * BK;   // batch-row tile
  int c  = tid & 31;          // col within tile
  int rg = tid >> 5;          // 0..7, row group (4 rows each)
  int lr = tid >> 3;          // loader row 0..31
  int lk = (tid & 7) * 4;     // loader k 0,4,...,28

  if (x_mode == 0 && tid < BK) stok[tid] = tok[b0 + tid];
  __syncthreads();

  double a_ir[4] = {0,0,0,0}, a_iz[4] = {0,0,0,0}, a_in[4] = {0,0,0,0};
  double a_hr[4] = {0,0,0,0}, a_hz[4] = {0,0,0,0}, a_hn[4] = {0,0,0,0};

  for (int k0 = 0; k0 < HH; k0 += BK) {
    // stage x tile
    if (x_mode == 0) {
      const float* xr = emb + (size_t)stok[lr] * HH + k0 + lk;
      xs[lr][lk + 0] = (double)xr[0]; xs[lr][lk + 1] = (double)xr[1];
      xs[lr][lk + 2] = (double)xr[2]; xs[lr][lk + 3] = (double)xr[3];
    } else {
      const double* xr = xf64 + (size_t)(b0 + lr) * HH + k0 + lk;
      xs[lr][lk + 0] = xr[0]; xs[lr][lk + 1] = xr[1];
      xs[lr][lk + 2] = xr[2]; xs[lr][lk + 3] = xr[3];
    }
    // stage h tile
    {
      const double* hr = hprev + (size_t)(b0 + lr) * HH + k0 + lk;
      hs[lr][lk + 0] = hr[0]; hs[lr][lk + 1] = hr[1];
      hs[lr][lk + 2] = hr[2]; hs[lr][lk + 3] = hr[3];
    }
    // stage 6 weight tiles (f32 in LDS to stay under the static-LDS cap)
    #pragma unroll
    for (int g = 0; g < 3; ++g) {
      const float* wi = Wih + ((size_t)g * HH + j0 + lr) * HH + k0 + lk;
      ws[g][lr][lk + 0] = wi[0]; ws[g][lr][lk + 1] = wi[1];
      ws[g][lr][lk + 2] = wi[2]; ws[g][lr][lk + 3] = wi[3];
      const float* wh = Whh + ((size_t)g * HH + j0 + lr) * HH + k0 + lk;
      ws[3 + g][lr][lk + 0] = wh[0]; ws[3 + g][lr][lk + 1] = wh[1];
      ws[3 + g][lr][lk + 2] = wh[2]; ws[3 + g][lr][lk + 3] = wh[3];
    }
    __syncthreads();

    #pragma unroll 4
    for (int kk = 0; kk < BK; ++kk) {
      double wr = (double)ws[0][c][kk], wz = (double)ws[1][c][kk], wn = (double)ws[2][c][kk];
      double vr = (double)ws[3][c][kk], vz = (double)ws[4][c][kk], vn = (double)ws[5][c][kk];
      #pragma unroll
      for (int i = 0; i < 4; ++i) {
        double xv = xs[rg * 4 + i][kk];
        double hv = hs[rg * 4 + i][kk];
        a_ir[i] = fma(xv, wr, a_ir[i]);
        a_iz[i] = fma(xv, wz, a_iz[i]);
        a_in[i] = fma(xv, wn, a_in[i]);
        a_hr[i] = fma(hv, vr, a_hr[i]);
        a_hz[i] = fma(hv, vz, a_hz[i]);
        a_hn[i] = fma(hv, vn, a_hn[i]);
      }
    }
    __syncthreads();
  }

  int j = j0 + c;
  double bir = (double)bih[j], biz = (double)bih[HH + j], bin_ = (double)bih[2 * HH + j];
  double bhr = (double)bhh[j], bhz = (double)bhh[HH + j], bhn = (double)bhh[2 * HH + j];
  #pragma unroll
  for (int i = 0; i < 4; ++i) {
    int b = b0 + rg * 4 + i;
    double ir = a_ir[i] + bir, iz = a_iz[i] + biz, inn = a_in[i] + bin_;
    double hr = a_hr[i] + bhr, hz = a_hz[i] + bhz, hn = a_hn[i] + bhn;
    double r = 1.0 / (1.0 + exp(-(ir + hr)));
    double z = 1.0 / (1.0 + exp(-(iz + hz)));
    double n = tanh(inn + r * hn);
    double hp = hprev[(size_t)b * HH + j];
    hout[(size_t)b * HH + j] = (1.0 - z) * n + z * hp;
  }
}

// ---------------- logits + gumbel-argmax sampling ----------------
// one block = 4 batch rows, 256 threads; each thread owns 2 columns.
__global__ void __launch_bounds__(256) sample_kernel(
    const float* __restrict__ Wout, const float* __restrict__ bout,
    const double* __restrict__ h2, float* __restrict__ out0,
    float* __restrict__ out1, int* __restrict__ tok, int t) {
  __shared__ double hsh[4][HH];
  __shared__ double rs[4][256];
  __shared__ int    ri[4][256];
  int tid = threadIdx.x;
  int b0 = blockIdx.x * 4;

  for (int i = tid; i < 4 * HH; i += 256)
    hsh[i >> 9][i & 511] = h2[(size_t)b0 * HH + i];
  __syncthreads();

  // subkey for step t: fold-like split of key(42) = (0,42)
  uint32_t k1t, k2t;
  threefry2x32(0u, 42u, 0u, (uint32_t)t, k1t, k2t);

  double sbest[4]; int ibest[4];
  #pragma unroll
  for (int half = 0; half < 2; ++half) {
    int cc = tid + half * 256;
    double acc[4] = {0, 0, 0, 0};
    const float* w = Wout + (size_t)cc * HH;
    for (int k = 0; k < HH; k += 4) {
      float4 wv = *(const float4*)(w + k);
      #pragma unroll
      for (int i = 0; i < 4; ++i) {
        acc[i] = fma(hsh[i][k + 0], (double)wv.x, acc[i]);
        acc[i] = fma(hsh[i][k + 1], (double)wv.y, acc[i]);
        acc[i] = fma(hsh[i][k + 2], (double)wv.z, acc[i]);
        acc[i] = fma(hsh[i][k + 3], (double)wv.w, acc[i]);
      }
    }
    double bo = (double)bout[cc];
    #pragma unroll
    for (int i = 0; i < 4; ++i) {
      int b = b0 + i;
      double lg = acc[i] + bo;
      out0[((size_t)b * TT + t) * NCC + cc] = (float)lg;
      // partitionable threefry random bits: w0 ^ w1 of cipher(subkey, (0, m))
      uint32_t o0, o1;
      threefry2x32(k1t, k2t, 0u, (uint32_t)(b * NCC + cc), o0, o1);
      uint32_t bits = o0 ^ o1;
      uint32_t ub = bits >> 9;
      float uf;
      if (ub == 0u) uf = 1.17549435e-38f;               // max(tiny, .)
      else          uf = __uint_as_float(0x3f800000u | ub) - 1.0f;
      double g = -log(-log((double)uf));
      double s = lg + g;
      if (half == 0) { sbest[i] = s; ibest[i] = cc; }
      else if (s > sbest[i]) { sbest[i] = s; ibest[i] = cc; }
    }
  }
  #pragma unroll
  for (int i = 0; i < 4; ++i) { rs[i][tid] = sbest[i]; ri[i][tid] = ibest[i]; }
  __syncthreads();
  for (int stride = 128; stride > 0; stride >>= 1) {
    if (tid < stride) {
      #pragma unroll
      for (int i = 0; i < 4; ++i) {
        double so = rs[i][tid + stride]; int io = ri[i][tid + stride];
        double sm = rs[i][tid];          int im = ri[i][tid];
        if (so > sm || (so == sm && io < im)) { rs[i][tid] = so; ri[i][tid] = io; }
      }
    }
    __syncthreads();
  }
  if (tid < 4) {
    int b = b0 + tid;
    int idx = ri[tid][0];
    tok[b] = idx;
    out1[(size_t)b * TT + t] = (float)idx;
  }
}

// ---------------- host launch ----------------
extern "C" void kernel_launch(void* const* d_in, const int* in_sizes, int n_in,
                              void* d_out, int out_size, void* d_ws, size_t ws_size,
                              hipStream_t stream) {
  const float* note  = (const float*)d_in[1];
  const float* genre = (const float*)d_in[2];
  const float* Whid  = (const float*)d_in[3];
  const float* bhid  = (const float*)d_in[4];
  const float* emb   = (const float*)d_in[5];
  const float* Wih1  = (const float*)d_in[6];
  const float* Whh1  = (const float*)d_in[7];
  const float* bih1  = (const float*)d_in[8];
  const float* bhh1  = (const float*)d_in[9];
  const float* Wih2  = (const float*)d_in[10];
  const float* Whh2  = (const float*)d_in[11];
  const float* bih2  = (const float*)d_in[12];
  const float* bhh2  = (const float*)d_in[13];
  const float* Wout  = (const float*)d_in[14];
  const float* bout  = (const float*)d_in[15];

  float* out0 = (float*)d_out;                      // [B, T, NC] logits
  float* out1 = out0 + (size_t)BB * TT * NCC;       // [B, T] tokens (as float)

  char* wsp = (char*)d_ws;
  double* h1a = (double*)wsp; wsp += (size_t)BB * HH * sizeof(double);
  double* h1b = (double*)wsp; wsp += (size_t)BB * HH * sizeof(double);
  double* h2a = (double*)wsp; wsp += (size_t)BB * HH * sizeof(double);
  double* h2b = (double*)wsp; wsp += (size_t)BB * HH * sizeof(double);
  int* tok = (int*)wsp;

  init_kernel<<<BB, 256, 0, stream>>>(note, genre, Whid, bhid, h1a, tok);

  double* c1 = h1a;
  double* c2 = h2a;
  dim3 ggrid(HH / BK, BB / BK);  // 16 x 16
  for (int t = 0; t < TT; ++t) {
    double* n1 = (c1 == h1a) ? h1b : h1a;
    double* n2 = (c2 == h2a) ? h2b : h2a;
    gru_kernel<<<ggrid, 256, 0, stream>>>(Wih1, Whh1, bih1, bhh1,
                                          c1, n1, (const double*)nullptr, emb, tok, 0);
    const double* hsrc2 = (t == 0) ? (const double*)n1 : (const double*)c2;
    gru_kernel<<<ggrid, 256, 0, stream>>>(Wih2, Whh2, bih2, bhh2,
                                          hsrc2, n2, n1, emb, tok, 1);
    sample_kernel<<<BB / 4, 256, 0, stream>>>(Wout, bout, n2, out0, out1, tok, t);
    c1 = n1;
    c2 = n2;
  }
}

// Round 2
// 45267.987 us; speedup vs baseline: 1.1317x; 1.1317x over previous
//
#include <hip/hip_runtime.h>
#include <stdint.h>

#define BB 512
#define TT 256
#define HH 512
#define NCC 512
#define KIN 272   // SKEL + GEN

// ---------------- threefry2x32 (JAX-exact, 20 rounds) ----------------
__device__ __forceinline__ void tf_round(uint32_t &x0, uint32_t &x1, int r) {
  x0 += x1;
  x1 = (x1 << r) | (x1 >> (32 - r));
  x1 ^= x0;
}

__device__ __forceinline__ void threefry2x32(uint32_t k0, uint32_t k1,
                                             uint32_t c0, uint32_t c1,
                                             uint32_t &o0, uint32_t &o1) {
  uint32_t ks2 = k0 ^ k1 ^ 0x1BD11BDAu;
  uint32_t x0 = c0 + k0, x1 = c1 + k1;
  tf_round(x0, x1, 13); tf_round(x0, x1, 15); tf_round(x0, x1, 26); tf_round(x0, x1, 6);
  x0 += k1;  x1 += ks2 + 1u;
  tf_round(x0, x1, 17); tf_round(x0, x1, 29); tf_round(x0, x1, 16); tf_round(x0, x1, 24);
  x0 += ks2; x1 += k0 + 2u;
  tf_round(x0, x1, 13); tf_round(x0, x1, 15); tf_round(x0, x1, 26); tf_round(x0, x1, 6);
  x0 += k0;  x1 += k1 + 3u;
  tf_round(x0, x1, 17); tf_round(x0, x1, 29); tf_round(x0, x1, 16); tf_round(x0, x1, 24);
  x0 += k1;  x1 += ks2 + 4u;
  tf_round(x0, x1, 13); tf_round(x0, x1, 15); tf_round(x0, x1, 26); tf_round(x0, x1, 6);
  x0 += ks2; x1 += k0 + 5u;
  o0 = x0; o1 = x1;
}

// ---------------- init: h1 = concat(note, genre) @ W_hid.T + b_hid; tok = 0 ----
__global__ void __launch_bounds__(256) init_kernel(
    const float* __restrict__ note, const float* __restrict__ genre,
    const float* __restrict__ Whid, const float* __restrict__ bhid,
    float* __restrict__ h1, int* __restrict__ tok) {
  int b = blockIdx.x;
  int tid = threadIdx.x;
  __shared__ double u[KIN];
  if (tid < 256) u[tid] = (double)note[b * 256 + tid];
  if (tid < 16)  u[256 + tid] = (double)genre[b * 16 + tid];
  if (tid == 0)  tok[b] = 0;
  __syncthreads();
  for (int j = tid; j < HH; j += 256) {
    double acc = 0.0;
    const float* w = Whid + (size_t)j * KIN;
    #pragma unroll 4
    for (int k = 0; k < KIN; ++k) acc = fma(u[k], (double)w[k], acc);
    h1[(size_t)b * HH + j] = (float)(acc + (double)bhid[j]);
  }
}

// ---------------- fused GRU cell step (f32, vectorized LDS, prefetch) --------
// 32(batch) x 32(hidden-col) tile per block, 256 threads, thread = 4 rows x 1 col.
// x_mode 0: x = emb[tok[b]]; x_mode 1: x = xf32 matrix.
#define BK 32
#define LDW 36   // LDS row stride (floats): 16B-aligned, conflict-minimal
__global__ void __launch_bounds__(256) gru_kernel(
    const float* __restrict__ Wih, const float* __restrict__ Whh,
    const float* __restrict__ bih, const float* __restrict__ bhh,
    const float* __restrict__ hprev, float* __restrict__ hout,
    const float* __restrict__ xf32,
    const float* __restrict__ emb, const int* __restrict__ tok, int x_mode) {
  __shared__ float xs[BK][LDW];
  __shared__ float hs[BK][LDW];
  __shared__ float ws[6][BK][LDW];
  __shared__ int   stok[BK];

  int tid = threadIdx.x;
  int j0 = blockIdx.x * BK;   // hidden-col tile
  int b0 = blockIdx.y * BK;   // batch-row tile
  int c  = tid & 31;          // col within tile
  int rg = tid >> 5;          // 0..7, row group (4 rows each)
  int lr = tid >> 3;          // loader row 0..31
  int lk = (tid & 7) * 4;     // loader k offset 0,4,...,28

  if (tid < BK) stok[tid] = (x_mode == 0) ? tok[b0 + tid] : 0;
  __syncthreads();

  // per-thread global staging bases
  const float* xbase = (x_mode == 0)
      ? emb + (size_t)stok[lr] * HH + lk
      : xf32 + (size_t)(b0 + lr) * HH + lk;
  const float* hbase = hprev + (size_t)(b0 + lr) * HH + lk;
  const float* wbase[6];
  #pragma unroll
  for (int g = 0; g < 3; ++g) {
    wbase[g]     = Wih + ((size_t)g * HH + j0 + lr) * HH + lk;
    wbase[3 + g] = Whh + ((size_t)g * HH + j0 + lr) * HH + lk;
  }

  float acc[6][4];
  #pragma unroll
  for (int g = 0; g < 6; ++g)
    #pragma unroll
    for (int i = 0; i < 4; ++i) acc[g][i] = 0.0f;

  // prefetch tile 0
  float4 px = *(const float4*)(xbase);
  float4 ph = *(const float4*)(hbase);
  float4 pw[6];
  #pragma unroll
  for (int g = 0; g < 6; ++g) pw[g] = *(const float4*)(wbase[g]);

  for (int k0 = 0; k0 < HH; k0 += BK) {
    __syncthreads();   // previous compute done reading LDS
    *(float4*)&xs[lr][lk] = px;
    *(float4*)&hs[lr][lk] = ph;
    #pragma unroll
    for (int g = 0; g < 6; ++g) *(float4*)&ws[g][lr][lk] = pw[g];
    __syncthreads();

    if (k0 + BK < HH) {  // prefetch next tile while computing this one
      px = *(const float4*)(xbase + k0 + BK);
      ph = *(const float4*)(hbase + k0 + BK);
      #pragma unroll
      for (int g = 0; g < 6; ++g) pw[g] = *(const float4*)(wbase[g] + k0 + BK);
    }

    #pragma unroll 2
    for (int kk = 0; kk < BK; kk += 4) {
      float4 wv[6];
      #pragma unroll
      for (int g = 0; g < 6; ++g) wv[g] = *(const float4*)&ws[g][c][kk];
      float4 xv[4], hv[4];
      #pragma unroll
      for (int i = 0; i < 4; ++i) {
        xv[i] = *(const float4*)&xs[rg * 4 + i][kk];
        hv[i] = *(const float4*)&hs[rg * 4 + i][kk];
      }
      #pragma unroll
      for (int i = 0; i < 4; ++i) {
        acc[0][i] = fmaf(xv[i].x, wv[0].x, acc[0][i]);
        acc[1][i] = fmaf(xv[i].x, wv[1].x, acc[1][i]);
        acc[2][i] = fmaf(xv[i].x, wv[2].x, acc[2][i]);
        acc[3][i] = fmaf(hv[i].x, wv[3].x, acc[3][i]);
        acc[4][i] = fmaf(hv[i].x, wv[4].x, acc[4][i]);
        acc[5][i] = fmaf(hv[i].x, wv[5].x, acc[5][i]);
        acc[0][i] = fmaf(xv[i].y, wv[0].y, acc[0][i]);
        acc[1][i] = fmaf(xv[i].y, wv[1].y, acc[1][i]);
        acc[2][i] = fmaf(xv[i].y, wv[2].y, acc[2][i]);
        acc[3][i] = fmaf(hv[i].y, wv[3].y, acc[3][i]);
        acc[4][i] = fmaf(hv[i].y, wv[4].y, acc[4][i]);
        acc[5][i] = fmaf(hv[i].y, wv[5].y, acc[5][i]);
        acc[0][i] = fmaf(xv[i].z, wv[0].z, acc[0][i]);
        acc[1][i] = fmaf(xv[i].z, wv[1].z, acc[1][i]);
        acc[2][i] = fmaf(xv[i].z, wv[2].z, acc[2][i]);
        acc[3][i] = fmaf(hv[i].z, wv[3].z, acc[3][i]);
        acc[4][i] = fmaf(hv[i].z, wv[4].z, acc[4][i]);
        acc[5][i] = fmaf(hv[i].z, wv[5].z, acc[5][i]);
        acc[0][i] = fmaf(xv[i].w, wv[0].w, acc[0][i]);
        acc[1][i] = fmaf(xv[i].w, wv[1].w, acc[1][i]);
        acc[2][i] = fmaf(xv[i].w, wv[2].w, acc[2][i]);
        acc[3][i] = fmaf(hv[i].w, wv[3].w, acc[3][i]);
        acc[4][i] = fmaf(hv[i].w, wv[4].w, acc[4][i]);
        acc[5][i] = fmaf(hv[i].w, wv[5].w, acc[5][i]);
      }
    }
  }

  int j = j0 + c;
  double bir = (double)bih[j], biz = (double)bih[HH + j], bin_ = (double)bih[2 * HH + j];
  double bhr = (double)bhh[j], bhz = (double)bhh[HH + j], bhn = (double)bhh[2 * HH + j];
  #pragma unroll
  for (int i = 0; i < 4; ++i) {
    int b = b0 + rg * 4 + i;
    double ir = (double)acc[0][i] + bir, iz = (double)acc[1][i] + biz;
    double inn = (double)acc[2][i] + bin_;
    double hr = (double)acc[3][i] + bhr, hz = (double)acc[4][i] + bhz;
    double hn = (double)acc[5][i] + bhn;
    double r = 1.0 / (1.0 + exp(-(ir + hr)));
    double z = 1.0 / (1.0 + exp(-(iz + hz)));
    double n = tanh(inn + r * hn);
    double hp = (double)hprev[(size_t)b * HH + j];
    hout[(size_t)b * HH + j] = (float)((1.0 - z) * n + z * hp);
  }
}

// ---------------- logits + gumbel-argmax sampling ----------------
// one block = 2 batch rows, 256 threads; each thread owns 2 columns.
__global__ void __launch_bounds__(256) sample_kernel(
    const float* __restrict__ Wout, const float* __restrict__ bout,
    const float* __restrict__ h2, float* __restrict__ out0,
    float* __restrict__ out1, int* __restrict__ tok, int t) {
  __shared__ double hsh[2][HH];
  __shared__ double rs[2][256];
  __shared__ int    ri[2][256];
  int tid = threadIdx.x;
  int b0 = blockIdx.x * 2;

  for (int i = tid; i < 2 * HH; i += 256)
    hsh[i >> 9][i & 511] = (double)h2[(size_t)b0 * HH + i];
  __syncthreads();

  // subkey for step t: fold-like split of key(42) = (0,42)
  uint32_t k1t, k2t;
  threefry2x32(0u, 42u, 0u, (uint32_t)t, k1t, k2t);

  double sbest[2]; int ibest[2];
  #pragma unroll
  for (int half = 0; half < 2; ++half) {
    int cc = tid + half * 256;
    double acc[2] = {0, 0};
    const float* w = Wout + (size_t)cc * HH;
    for (int k = 0; k < HH; k += 4) {
      float4 wv = *(const float4*)(w + k);
      #pragma unroll
      for (int i = 0; i < 2; ++i) {
        acc[i] = fma(hsh[i][k + 0], (double)wv.x, acc[i]);
        acc[i] = fma(hsh[i][k + 1], (double)wv.y, acc[i]);
        acc[i] = fma(hsh[i][k + 2], (double)wv.z, acc[i]);
        acc[i] = fma(hsh[i][k + 3], (double)wv.w, acc[i]);
      }
    }
    double bo = (double)bout[cc];
    #pragma unroll
    for (int i = 0; i < 2; ++i) {
      int b = b0 + i;
      double lg = acc[i] + bo;
      out0[((size_t)b * TT + t) * NCC + cc] = (float)lg;
      // partitionable threefry random bits: w0 ^ w1 of cipher(subkey, (0, m))
      uint32_t o0, o1;
      threefry2x32(k1t, k2t, 0u, (uint32_t)(b * NCC + cc), o0, o1);
      uint32_t bits = o0 ^ o1;
      uint32_t ub = bits >> 9;
      float uf;
      if (ub == 0u) uf = 1.17549435e-38f;               // max(tiny, .)
      else          uf = __uint_as_float(0x3f800000u | ub) - 1.0f;
      double g = -log(-log((double)uf));
      double s = lg + g;
      if (half == 0) { sbest[i] = s; ibest[i] = cc; }
      else if (s > sbest[i]) { sbest[i] = s; ibest[i] = cc; }
    }
  }
  #pragma unroll
  for (int i = 0; i < 2; ++i) { rs[i][tid] = sbest[i]; ri[i][tid] = ibest[i]; }
  __syncthreads();
  for (int stride = 128; stride > 0; stride >>= 1) {
    if (tid < stride) {
      #pragma unroll
      for (int i = 0; i < 2; ++i) {
        double so = rs[i][tid + stride]; int io = ri[i][tid + stride];
        double sm = rs[i][tid];          int im = ri[i][tid];
        if (so > sm || (so == sm && io < im)) { rs[i][tid] = so; ri[i][tid] = io; }
      }
    }
    __syncthreads();
  }
  if (tid < 2) {
    int b = b0 + tid;
    int idx = ri[tid][0];
    tok[b] = idx;
    out1[(size_t)b * TT + t] = (float)idx;
  }
}

// ---------------- host launch ----------------
extern "C" void kernel_launch(void* const* d_in, const int* in_sizes, int n_in,
                              void* d_out, int out_size, void* d_ws, size_t ws_size,
                              hipStream_t stream) {
  const float* note  = (const float*)d_in[1];
  const float* genre = (const float*)d_in[2];
  const float* Whid  = (const float*)d_in[3];
  const float* bhid  = (const float*)d_in[4];
  const float* emb   = (const float*)d_in[5];
  const float* Wih1  = (const float*)d_in[6];
  const float* Whh1  = (const float*)d_in[7];
  const float* bih1  = (const float*)d_in[8];
  const float* bhh1  = (const float*)d_in[9];
  const float* Wih2  = (const float*)d_in[10];
  const float* Whh2  = (const float*)d_in[11];
  const float* bih2  = (const float*)d_in[12];
  const float* bhh2  = (const float*)d_in[13];
  const float* Wout  = (const float*)d_in[14];
  const float* bout  = (const float*)d_in[15];

  float* out0 = (float*)d_out;                      // [B, T, NC] logits
  float* out1 = out0 + (size_t)BB * TT * NCC;       // [B, T] tokens (as float)

  char* wsp = (char*)d_ws;
  float* h1a = (float*)wsp; wsp += (size_t)BB * HH * sizeof(float);
  float* h1b = (float*)wsp; wsp += (size_t)BB * HH * sizeof(float);
  float* h2a = (float*)wsp; wsp += (size_t)BB * HH * sizeof(float);
  float* h2b = (float*)wsp; wsp += (size_t)BB * HH * sizeof(float);
  int* tok = (int*)wsp;

  init_kernel<<<BB, 256, 0, stream>>>(note, genre, Whid, bhid, h1a, tok);

  float* c1 = h1a;
  float* c2 = h2a;
  dim3 ggrid(HH / BK, BB / BK);  // 16 x 16
  for (int t = 0; t < TT; ++t) {
    float* n1 = (c1 == h1a) ? h1b : h1a;
    float* n2 = (c2 == h2a) ? h2b : h2a;
    gru_kernel<<<ggrid, 256, 0, stream>>>(Wih1, Whh1, bih1, bhh1,
                                          c1, n1, (const float*)nullptr, emb, tok, 0);
    const float* hsrc2 = (t == 0) ? (const float*)n1 : (const float*)c2;
    gru_kernel<<<ggrid, 256, 0, stream>>>(Wih2, Whh2, bih2, bhh2,
                                          hsrc2, n2, n1, emb, tok, 1);
    sample_kernel<<<BB / 2, 256, 0, stream>>>(Wout, bout, n2, out0, out1, tok, t);
    c1 = n1;
    c2 = n2;
  }
}